// Round 1
// baseline (586.874 us; speedup 1.0000x reference)
//
#include <hip/hip_runtime.h>

#define GO_H   19
#define NCELL  361              // 19*19
#define G      4                // boards per block (65536 % 4 == 0)
#define NROWS  (G * GO_H)       // 76 row-threads
#define MASK19 0x7FFFFu
#define OUTF   (G * 5 * NCELL)  // 7220 output floats per block
#define INF4   ((G * 2 * NCELL) / 4)  // 722 float4 of input per block

__global__ __launch_bounds__(256) void go_features_kernel(
    const float* __restrict__ stones,      // (B, 2, 19, 19)
    const int*   __restrict__ cur_player,  // (B,)
    const int*   __restrict__ ko,          // (B, 2)
    float*       __restrict__ out,         // (B, 5, 19, 19)
    int B)
{
    // out_s doubles as input staging (2888 floats) before it is overwritten
    // by the 7220 output floats in phase C (after two barriers).
    __shared__ __align__(16) float out_s[OUTF];
    __shared__ unsigned c_m[G][GO_H];   // cur bitmask per row
    __shared__ unsigned o_m[G][GO_H];   // opp bitmask per row
    __shared__ unsigned e_m[G][GO_H];   // empty bitmask per row
    __shared__ unsigned w_m[G][GO_H];   // weak bitmask per row
    __shared__ float    cpf_s[G];
    __shared__ int      kor_s[G];       // ko row (or -1)
    __shared__ unsigned kcm_s[G];       // ko column bitmask

    const int tid = threadIdx.x;
    const int gb  = blockIdx.x * G;

    // ---- Phase 0: stage group input into LDS as float4 (coalesced) ----
    {
        const float4* in4 = (const float4*)(stones + (size_t)gb * (2 * NCELL));
        float4* s4 = (float4*)out_s;
        for (int i = tid; i < INF4; i += 256) s4[i] = in4[i];
    }
    __syncthreads();

    // ---- Phase A: one thread per (board,row) builds bitmasks ----
    unsigned c = 0, o = 0, e = 0;
    int g = 0, r = 0;
    if (tid < NROWS) {
        g = tid / GO_H;
        r = tid - g * GO_H;
        const int b  = gb + g;
        const int cp = cur_player[b];
        const float* bp = out_s + g * (2 * NCELL) + r * GO_H;
        unsigned p0 = 0, p1 = 0;
        #pragma unroll
        for (int j = 0; j < GO_H; ++j) {
            if (bp[j] > 0.5f)         p0 |= 1u << j;
            if (bp[NCELL + j] > 0.5f) p1 |= 1u << j;
        }
        c = cp ? p1 : p0;
        o = cp ? p0 : p1;
        e = ~(p0 | p1) & MASK19;
        c_m[g][r] = c;  o_m[g][r] = o;  e_m[g][r] = e;
        if (r == 0) {
            cpf_s[g] = (float)cp;
            int kr = ko[2 * b], kc = ko[2 * b + 1];
            int rr = min(max(kr, 0), GO_H - 1);
            int cc = min(max(kc, 0), GO_H - 1);
            kor_s[g] = (kr >= 0) ? rr : -1;
            kcm_s[g] = 1u << cc;
        }
    }
    __syncthreads();

    // ---- Phase B: weak stones, legal(no-weak), cur_lib bitplanes ----
    unsigned w = 0, legal_nw = 0, l0 = 0, l1 = 0, l2 = 0;
    if (tid < NROWS) {
        // weak = opp & (exactly one opp neighbor)
        unsigned oU = r ? o_m[g][r-1] : 0u;
        unsigned oD = (r < GO_H-1) ? o_m[g][r+1] : 0u;
        unsigned a  = (o << 1) & MASK19, bq = o >> 1;
        unsigned x1  = a ^ bq ^ oU ^ oD;                       // odd count
        unsigned at2 = (a & bq) | (oU & oD) | ((a | bq) & (oU | oD));
        w = o & x1 & ~at2;
        w_m[g][r] = w;

        // legal (without weak contribution): empty & nbrOr(empty)
        unsigned eU = r ? e_m[g][r-1] : 0u;
        unsigned eD = (r < GO_H-1) ? e_m[g][r+1] : 0u;
        legal_nw = e & ((e << 1) | (e >> 1) | eU | eD);

        // cur_lib = count of cur neighbors (0..4) as 3 bitplanes, masked by empty
        unsigned cU = r ? c_m[g][r-1] : 0u;
        unsigned cD = (r < GO_H-1) ? c_m[g][r+1] : 0u;
        unsigned ca = (c << 1) & MASK19, cb = c >> 1;
        unsigned s1 = ca ^ cb, k1 = ca & cb;
        unsigned s2 = s1 ^ cU, k2 = s1 & cU;
        unsigned s3 = s2 ^ cD, k3 = s2 & cD;
        l0 = s3 & e;                                   // bit0 of count
        l1 = (k1 ^ k2 ^ k3) & e;                       // bit1
        l2 = ((k1 & k2) | (k1 & k3) | (k2 & k3)) & e;  // bit2
    }
    __syncthreads();

    // ---- Phase C: finish legal with weak neighbors, expand to floats in LDS ----
    if (tid < NROWS) {
        unsigned wU = r ? w_m[g][r-1] : 0u;
        unsigned wD = (r < GO_H-1) ? w_m[g][r+1] : 0u;
        unsigned legal = legal_nw | (e & (((w << 1) & MASK19) | (w >> 1) | wU | wD));
        if (r == kor_s[g]) legal &= ~kcm_s[g];
        const float cpf = cpf_s[g];
        float* ob = out_s + g * (5 * NCELL) + r * GO_H;
        #pragma unroll
        for (int j = 0; j < GO_H; ++j) {
            ob[j]             = (float)((c >> j) & 1u);
            ob[NCELL + j]     = (float)((o >> j) & 1u);
            ob[2 * NCELL + j] = (float)((legal >> j) & 1u);
            ob[3 * NCELL + j] = (float)(((l0 >> j) & 1u) |
                                        (((l1 >> j) & 1u) << 1) |
                                        (((l2 >> j) & 1u) << 2));
            ob[4 * NCELL + j] = cpf;
        }
    }
    __syncthreads();

    // ---- Phase D: single coalesced float4 stream LDS -> global ----
    {
        const float4* s4 = (const float4*)out_s;
        float4* o4 = (float4*)(out + (size_t)gb * (5 * NCELL));  // 16B-aligned (gb%4==0)
        for (int i = tid; i < OUTF / 4; i += 256) o4[i] = s4[i];
    }
}

extern "C" void kernel_launch(void* const* d_in, const int* in_sizes, int n_in,
                              void* d_out, int out_size, void* d_ws, size_t ws_size,
                              hipStream_t stream) {
    const float* stones     = (const float*)d_in[0];
    const int*   cur_player = (const int*)d_in[1];
    const int*   ko         = (const int*)d_in[2];
    float*       out        = (float*)d_out;

    const int B = in_sizes[1];          // current_player has B elements
    const int nblocks = B / G;          // 65536 / 4 = 16384
    go_features_kernel<<<nblocks, 256, 0, stream>>>(stones, cur_player, ko, out, B);
}